// Round 7
// baseline (224.959 us; speedup 1.0000x reference)
//
#include <hip/hip_runtime.h>

// YOLO loss, 3 levels. Inputs (fp32):
//   d_in[0..2] = pred (N=16, C=255, H, W), d_in[3..5] = label (N, H, W, 3, 85)
// Output: d_out = [reg, conf, prob] fp32.
//
// R7: R6 showed only the harness ws-poison fill (41 us) in top-5; our 4
// dependent dispatches (memset/scan/fused/finalize) cost mostly gaps+drains.
// Collapse to 2 dispatches: 256 B memset (counts+sync) + ONE persistent
// kernel:
//   phase 1: conf-only gather scan (1 x 4B load per cell), compact positives
//   [conf blocks prefetch their 5 feature-plane values BEFORE the barrier]
//   grid barrier (device-scope atomics; 714 blocks x 4 waves = 2856 waves,
//   all co-resident on 8192-wave device -> safe)
//   phase 2: blocks <666 conf loss; blocks 666..713 positives (1 wave/box,
//   prob channels spread across lanes)
//   epilogue: last-done block reduces partials -> out (others exit).

#define NIMG 16
#define MAXB 64

// per-level cell counts: N*3*H*W
#define C0 (16 * 3 * 52 * 52)   // 129792
#define C1 (16 * 3 * 26 * 26)   // 32448
#define C2 (16 * 3 * 13 * 13)   // 8112
#define CTOT (C0 + C1 + C2)     // 170352
#define NBLK ((CTOT + 255) / 256)  // 666 conf blocks
#define NALL (NBLK + 48)           // 714 total blocks

// workspace layout (bytes); first 256 B zeroed by the memset
#define WS_COUNTS   0           // 48 ints
#define WS_SYNC     192         // 2 ints: [0]=barrier arrive, [1]=done count
#define WS_BOXES    256         // 48*64 float4 = 49152
#define WS_CELLIDS  49408       // 48*64 int    = 12288
#define WS_PARTIAL  65536       // float[3][1024]: [0]=reg(48), [1]=conf(666), [2]=prob(48)

__device__ __constant__ float d_anchors[3][3][2] = {
    {{12.f, 16.f}, {19.f, 36.f}, {40.f, 28.f}},
    {{36.f, 75.f}, {76.f, 55.f}, {72.f, 146.f}},
    {{142.f, 110.f}, {192.f, 243.f}, {459.f, 401.f}}};

__device__ __forceinline__ float bce_logits(float x, float t) {
    return fmaxf(x, 0.f) - x * t + log1pf(expf(-fabsf(x)));
}

__global__ __launch_bounds__(256) void yolo_all(
        const float* __restrict__ f0,
        const float* __restrict__ f1,
        const float* __restrict__ f2,
        const float* __restrict__ l0,
        const float* __restrict__ l1,
        const float* __restrict__ l2,
        int* __restrict__ counts,
        int* __restrict__ sync,
        float4* __restrict__ boxes,
        int* __restrict__ cellids,
        float* __restrict__ partial,
        float* __restrict__ out) {
    const int lane = threadIdx.x & 63;
    const int wid  = threadIdx.x >> 6;
    const int tid  = blockIdx.x * blockDim.x + threadIdx.x;

    // ---------------- Phase 1: conf-only gather, compact positives ----------
    if (tid < CTOT) {
        const float* lab;
        int level, cell, hw3;
        if (tid < C0)           { level = 0; cell = tid;           lab = l0; hw3 = 3 * 52 * 52; }
        else if (tid < C0 + C1) { level = 1; cell = tid - C0;      lab = l1; hw3 = 3 * 26 * 26; }
        else                    { level = 2; cell = tid - C0 - C1; lab = l2; hw3 = 3 * 13 * 13; }
        const float* lp = lab + (size_t)cell * 85;
        float c = lp[4];                 // only load for 99.92% of threads
        if (c > 0.f) {
            int n = cell / hw3;
            int p = atomicAdd(&counts[level * NIMG + n], 1);
            if (p < MAXB) {
                float4 b;
                b.x = lp[0]; b.y = lp[1]; b.z = lp[2]; b.w = lp[3];
                boxes[(level * NIMG + n) * MAXB + p] = b;
                cellids[(level * NIMG + n) * MAXB + p] = cell;
            }
        }
    }

    // ---- prefetch conf-phase feature values (independent of labels) --------
    const bool is_conf = (blockIdx.x < NBLK);
    float rx = 0.f, ry = 0.f, rw = 0.f, rh = 0.f, rc = 0.f;
    int level = 0, cell = 0, W = 52, HW = 52 * 52;
    float stride = 8.f;
    const float* fcur = f0;
    if (is_conf && tid < CTOT) {
        if (tid < C0)           { level = 0; cell = tid;           fcur = f0; W = 52; HW = 52 * 52; stride = 8.f; }
        else if (tid < C0 + C1) { level = 1; cell = tid - C0;      fcur = f1; W = 26; HW = 26 * 26; stride = 16.f; }
        else                    { level = 2; cell = tid - C0 - C1; fcur = f2; W = 13; HW = 13 * 13; stride = 32.f; }
        int hw = cell % HW;
        int na = cell / HW;
        int a = na % 3;
        int n = na / 3;
        const float* fp = fcur + (size_t)n * 255 * HW + (size_t)a * 85 * HW + hw;
        rx = fp[0];
        ry = fp[HW];
        rw = fp[2 * HW];
        rh = fp[3 * HW];
        rc = fp[4 * HW];
    }

    // ---------------- grid barrier (all 714 blocks co-resident) ------------
    __syncthreads();
    if (threadIdx.x == 0) {
        __threadfence();                         // publish boxes/cellids/counts
        atomicAdd(&sync[0], 1);
        while (atomicAdd(&sync[0], 0) < NALL)    // device-scope spin
            __builtin_amdgcn_s_sleep(2);
        __threadfence();                         // acquire
    }
    __syncthreads();

    // ---------------- Phase 2 ----------------
    if (is_conf) {
        float conf = 0.f;
        if (tid < CTOT) {
            int hw = cell % HW;
            int na = cell / HW;
            int a = na % 3;
            int n = na / 3;
            int w = hw % W;
            int h = hw / W;
            int cell_lab = (n * HW + hw) * 3 + a;

            float aw = d_anchors[level][a][0];
            float ah = d_anchors[level][a][1];
            float px = (1.f / (1.f + expf(-rx)) + (float)w) * stride;
            float py = (1.f / (1.f + expf(-ry)) + (float)h) * stride;
            float pw = expf(rw) * aw;
            float ph = expf(rh) * ah;

            int m = counts[level * NIMG + n];
            if (m > MAXB) m = MAXB;
            int base = (level * NIMG + n) * MAXB;
            float parea = pw * ph;
            float pl = px - pw * 0.5f, pr = px + pw * 0.5f;
            float pt = py - ph * 0.5f, pb = py + ph * 0.5f;
            float maxiou = 0.f;
            bool ispos = false;
            for (int i = 0; i < m; ++i) {
                float4 b = boxes[base + i];
                if (cellids[base + i] == cell_lab) ispos = true;
                float tl = b.x - b.z * 0.5f, tr = b.x + b.z * 0.5f;
                float tt = b.y - b.w * 0.5f, tb = b.y + b.w * 0.5f;
                float iw = fmaxf(fminf(pr, tr) - fmaxf(pl, tl), 0.f);
                float ih = fmaxf(fminf(pb, tb) - fmaxf(pt, tt), 0.f);
                float inter = iw * ih;
                float uni = parea + b.z * b.w - inter;
                float iou = inter / fmaxf(uni, 1e-9f);
                maxiou = fmaxf(maxiou, iou);
            }
            if (ispos)              conf = bce_logits(rc, 1.f);
            else if (maxiou < 0.5f) conf = bce_logits(rc, 0.f);
        }
        for (int off = 32; off > 0; off >>= 1) conf += __shfl_down(conf, off);
        __shared__ float sc[4];
        if (lane == 0) sc[wid] = conf;
        __syncthreads();
        if (threadIdx.x == 0)
            partial[1 * 1024 + blockIdx.x] = sc[0] + sc[1] + sc[2] + sc[3];
    } else {
        // ---- positives: one wave per box ----
        int pb = blockIdx.x - NBLK;          // 0..47 = (level, image)
        int lv = pb / NIMG;
        int n = pb % NIMG;
        const float *f, *lab;
        int Wp, HWp; float strp;
        if (lv == 0)      { f = f0; lab = l0; Wp = 52; HWp = 52 * 52; strp = 8.f; }
        else if (lv == 1) { f = f1; lab = l1; Wp = 26; HWp = 26 * 26; strp = 16.f; }
        else              { f = f2; lab = l2; Wp = 13; HWp = 13 * 13; strp = 32.f; }

        int m = counts[pb];
        if (m > MAXB) m = MAXB;
        int bbase = pb * MAXB;

        float reg_acc = 0.f, prob_acc = 0.f;
        for (int i = wid; i < m; i += 4) {   // one wave per positive box
            int pcell = cellids[bbase + i];  // (n*HW + hw)*3 + a
            float4 b = boxes[bbase + i];
            int a = pcell % 3;
            int hw = (pcell / 3) % HWp;
            int w = hw % Wp;
            int h = hw / Wp;
            const float* fp = f + ((size_t)n * 255 + (size_t)a * 85) * HWp + hw;
            const float* lp = lab + (size_t)pcell * 85;

            // lanes 0..39: prob ch (5+lane) & (45+lane); lanes 40..43: raw xy/wh
            int ch1 = (lane < 40) ? (5 + lane) : ((lane < 44) ? (lane - 40) : 0);
            float g1 = fp[(size_t)ch1 * HWp];
            float g2 = fp[(size_t)((lane < 40) ? (45 + lane) : 0) * HWp];
            float t1 = lp[(lane < 40) ? (5 + lane) : 0];
            float t2 = lp[(lane < 40) ? (45 + lane) : 0];

            float pp = (lane < 40) ? (bce_logits(g1, t1) + bce_logits(g2, t2)) : 0.f;
            for (int off = 32; off > 0; off >>= 1) pp += __shfl_down(pp, off);

            float prx = __shfl(g1, 40);
            float pry = __shfl(g1, 41);
            float prw = __shfl(g1, 42);
            float prh = __shfl(g1, 43);
            if (lane == 0) {
                prob_acc += pp;
                float aw = d_anchors[lv][a][0];
                float ah = d_anchors[lv][a][1];
                float ox = b.x / strp - (float)w;
                float oy = b.y / strp - (float)h;
                float ow = logf(b.z / aw + 1e-7f);
                float oh = logf(b.w / ah + 1e-7f);
                float scale = 2.f - b.z * b.w * (1.f / (416.f * 416.f));
                float dw = prw - ow, dh = prh - oh;
                reg_acc += scale * (bce_logits(prx, ox) + bce_logits(pry, oy))
                         + scale * 0.5f * (dw * dw + dh * dh);
            }
        }
        __shared__ float sp[2][4];
        if (lane == 0) { sp[0][wid] = reg_acc; sp[1][wid] = prob_acc; }
        __syncthreads();
        if (threadIdx.x == 0) {
            partial[0 * 1024 + pb] = sp[0][0] + sp[0][1] + sp[0][2] + sp[0][3];
            partial[2 * 1024 + pb] = sp[1][0] + sp[1][1] + sp[1][2] + sp[1][3];
        }
    }

    // ---------------- epilogue: last-done block finalizes -------------------
    __shared__ int amlast;
    __syncthreads();
    if (threadIdx.x == 0) {
        __threadfence();                         // publish partial[]
        int d = atomicAdd(&sync[1], 1);
        amlast = (d == NALL - 1) ? 1 : 0;
    }
    __syncthreads();
    if (amlast) {
        __threadfence();                         // acquire others' partials
        float a0 = 0.f, a1 = 0.f, a2 = 0.f;
        for (int i = threadIdx.x; i < NBLK; i += 256) {
            a1 += partial[1 * 1024 + i];
            if (i < 48) {
                a0 += partial[0 * 1024 + i];
                a2 += partial[2 * 1024 + i];
            }
        }
        for (int off = 32; off > 0; off >>= 1) {
            a0 += __shfl_down(a0, off);
            a1 += __shfl_down(a1, off);
            a2 += __shfl_down(a2, off);
        }
        __shared__ float s[3][4];
        if (lane == 0) { s[0][wid] = a0; s[1][wid] = a1; s[2][wid] = a2; }
        __syncthreads();
        if (threadIdx.x == 0) {
            out[0] = (s[0][0] + s[0][1] + s[0][2] + s[0][3]) * (1.f / 16.f);
            out[1] = (s[1][0] + s[1][1] + s[1][2] + s[1][3]) * (1.f / 16.f);
            out[2] = (s[2][0] + s[2][1] + s[2][2] + s[2][3]) * (1.f / 16.f);
        }
    }
}

extern "C" void kernel_launch(void* const* d_in, const int* in_sizes, int n_in,
                              void* d_out, int out_size, void* d_ws, size_t ws_size,
                              hipStream_t stream) {
    const float* f0 = (const float*)d_in[0];
    const float* f1 = (const float*)d_in[1];
    const float* f2 = (const float*)d_in[2];
    const float* l0 = (const float*)d_in[3];
    const float* l1 = (const float*)d_in[4];
    const float* l2 = (const float*)d_in[5];
    float* out = (float*)d_out;

    int*    counts  = (int*)((char*)d_ws + WS_COUNTS);
    int*    syncp   = (int*)((char*)d_ws + WS_SYNC);
    float4* boxes   = (float4*)((char*)d_ws + WS_BOXES);
    int*    cellids = (int*)((char*)d_ws + WS_CELLIDS);
    float*  partial = (float*)((char*)d_ws + WS_PARTIAL);

    hipMemsetAsync(d_ws, 0, 256, stream);   // zero counts + sync

    yolo_all<<<NALL, 256, 0, stream>>>(f0, f1, f2, l0, l1, l2,
                                       counts, syncp, boxes, cellids,
                                       partial, out);
}

// Round 8
// 145.891 us; speedup vs baseline: 1.5420x; 1.5420x over previous
//
#include <hip/hip_runtime.h>

// YOLO loss, 3 levels. Inputs (fp32):
//   d_in[0..2] = pred (N=16, C=255, H, W), d_in[3..5] = label (N, H, W, 3, 85)
// Output: d_out = [reg, conf, prob] fp32.
//
// R8 = R6 champion structure (memset -> scan -> loss) with finalize folded
// into the loss kernel via R7's proven done-counter epilogue (one atomicAdd
// per block, NO polling -- R7's spin-barrier RMW storm was the 100us
// regression). Positive blocks are scheduled first (blockIdx 0..47) so their
// serial gather chains start at dispatch head.
//  scan:  conf-only gather (one 4B load per cell, stride 340 B) -> compact
//         positive boxes per (level,image). ~11 MB of cachelines.
//  loss:  blocks 0..47 = positives, ONE WAVE per box, prob channels spread
//         across lanes (2 wave-wide gathers); blocks 48..713 = conf loss per
//         cell (coalesced channel planes, zero label reads); last-done block
//         reduces partials -> out.

#define NIMG 16
#define MAXB 64

// per-level cell counts: N*3*H*W
#define C0 (16 * 3 * 52 * 52)   // 129792
#define C1 (16 * 3 * 26 * 26)   // 32448
#define C2 (16 * 3 * 13 * 13)   // 8112
#define CTOT (C0 + C1 + C2)     // 170352
#define NBLK ((CTOT + 255) / 256)  // 666 conf blocks
#define NPOS 48
#define NALL (NBLK + NPOS)         // 714 total blocks

// workspace layout (bytes); first 256 B zeroed by the memset
#define WS_COUNTS   0           // 48 ints
#define WS_SYNC     192         // 1 int: done count
#define WS_BOXES    256         // 48*64 float4 = 49152
#define WS_CELLIDS  49408       // 48*64 int    = 12288
#define WS_PARTIAL  65536       // float[3][1024]: [0]=reg(48), [1]=conf(666), [2]=prob(48)

__device__ __constant__ float d_anchors[3][3][2] = {
    {{12.f, 16.f}, {19.f, 36.f}, {40.f, 28.f}},
    {{36.f, 75.f}, {76.f, 55.f}, {72.f, 146.f}},
    {{142.f, 110.f}, {192.f, 243.f}, {459.f, 401.f}}};

__device__ __forceinline__ float bce_logits(float x, float t) {
    return fmaxf(x, 0.f) - x * t + log1pf(expf(-fabsf(x)));
}

// ---------------- Kernel A: conf-only gather + positive compaction ----------
__global__ void scan_labels(const float* __restrict__ l0,
                            const float* __restrict__ l1,
                            const float* __restrict__ l2,
                            int* __restrict__ counts,
                            float4* __restrict__ boxes,
                            int* __restrict__ cellids) {
    int rec = blockIdx.x * blockDim.x + threadIdx.x;
    if (rec >= CTOT) return;

    const float* lab;
    int level, cell, hw3;
    if (rec < C0)           { level = 0; cell = rec;           lab = l0; hw3 = 3 * 52 * 52; }
    else if (rec < C0 + C1) { level = 1; cell = rec - C0;      lab = l1; hw3 = 3 * 26 * 26; }
    else                    { level = 2; cell = rec - C0 - C1; lab = l2; hw3 = 3 * 13 * 13; }

    const float* lp = lab + (size_t)cell * 85;
    float c = lp[4];                     // the only load for 99.92% of threads
    if (c > 0.f) {
        int n = cell / hw3;
        int p = atomicAdd(&counts[level * NIMG + n], 1);
        if (p < MAXB) {
            float4 b;
            b.x = lp[0]; b.y = lp[1]; b.z = lp[2]; b.w = lp[3];
            boxes[(level * NIMG + n) * MAXB + p] = b;
            cellids[(level * NIMG + n) * MAXB + p] = cell;
        }
    }
}

// ---------------- Kernel B: pos (blocks 0..47) + conf + last-block finalize --
__global__ __launch_bounds__(256) void loss_fused(
        const float* __restrict__ f0,
        const float* __restrict__ f1,
        const float* __restrict__ f2,
        const float* __restrict__ l0,
        const float* __restrict__ l1,
        const float* __restrict__ l2,
        const int* __restrict__ counts,
        int* __restrict__ syncp,
        const float4* __restrict__ boxes,
        const int* __restrict__ cellids,
        float* __restrict__ partial,
        float* __restrict__ out) {
    int lane = threadIdx.x & 63;
    int wid = threadIdx.x >> 6;

    if (blockIdx.x < NPOS) {
        // ---- positives: one wave per box ----
        int pb = blockIdx.x;                 // 0..47 = (level, image)
        int lv = pb / NIMG;
        int n = pb % NIMG;
        const float *f, *lab;
        int Wp, HWp; float strp;
        if (lv == 0)      { f = f0; lab = l0; Wp = 52; HWp = 52 * 52; strp = 8.f; }
        else if (lv == 1) { f = f1; lab = l1; Wp = 26; HWp = 26 * 26; strp = 16.f; }
        else              { f = f2; lab = l2; Wp = 13; HWp = 13 * 13; strp = 32.f; }

        int m = counts[pb];
        if (m > MAXB) m = MAXB;
        int bbase = pb * MAXB;

        float reg_acc = 0.f, prob_acc = 0.f;
        for (int i = wid; i < m; i += 4) {   // one wave per positive box
            int pcell = cellids[bbase + i];  // (n*HW + hw)*3 + a
            float4 b = boxes[bbase + i];
            int a = pcell % 3;
            int hw = (pcell / 3) % HWp;
            int w = hw % Wp;
            int h = hw / Wp;
            const float* fp = f + ((size_t)n * 255 + (size_t)a * 85) * HWp + hw;
            const float* lp = lab + (size_t)pcell * 85;

            // lanes 0..39: prob ch (5+lane) & (45+lane); lanes 40..43: raw xy/wh
            int ch1 = (lane < 40) ? (5 + lane) : ((lane < 44) ? (lane - 40) : 0);
            float g1 = fp[(size_t)ch1 * HWp];
            float g2 = fp[(size_t)((lane < 40) ? (45 + lane) : 0) * HWp];
            float t1 = lp[(lane < 40) ? (5 + lane) : 0];
            float t2 = lp[(lane < 40) ? (45 + lane) : 0];

            float pp = (lane < 40) ? (bce_logits(g1, t1) + bce_logits(g2, t2)) : 0.f;
            for (int off = 32; off > 0; off >>= 1) pp += __shfl_down(pp, off);

            float prx = __shfl(g1, 40);
            float pry = __shfl(g1, 41);
            float prw = __shfl(g1, 42);
            float prh = __shfl(g1, 43);
            if (lane == 0) {
                prob_acc += pp;
                float aw = d_anchors[lv][a][0];
                float ah = d_anchors[lv][a][1];
                float ox = b.x / strp - (float)w;
                float oy = b.y / strp - (float)h;
                float ow = logf(b.z / aw + 1e-7f);
                float oh = logf(b.w / ah + 1e-7f);
                float scale = 2.f - b.z * b.w * (1.f / (416.f * 416.f));
                float dw = prw - ow, dh = prh - oh;
                reg_acc += scale * (bce_logits(prx, ox) + bce_logits(pry, oy))
                         + scale * 0.5f * (dw * dw + dh * dh);
            }
        }
        __shared__ float sp[2][4];
        if (lane == 0) { sp[0][wid] = reg_acc; sp[1][wid] = prob_acc; }
        __syncthreads();
        if (threadIdx.x == 0) {
            partial[0 * 1024 + pb] = sp[0][0] + sp[0][1] + sp[0][2] + sp[0][3];
            partial[2 * 1024 + pb] = sp[1][0] + sp[1][1] + sp[1][2] + sp[1][3];
        }
    } else {
        // ---- conf loss per cell; no label reads ----
        int cb = blockIdx.x - NPOS;          // 0..NBLK-1
        int gid = cb * blockDim.x + threadIdx.x;
        float conf = 0.f;

        if (gid < CTOT) {
            const float* f;
            int level, cell, W, HW;
            float stride;
            if (gid < C0)           { level = 0; cell = gid;           f = f0; W = 52; HW = 52 * 52; stride = 8.f; }
            else if (gid < C0 + C1) { level = 1; cell = gid - C0;      f = f1; W = 26; HW = 26 * 26; stride = 16.f; }
            else                    { level = 2; cell = gid - C0 - C1; f = f2; W = 13; HW = 13 * 13; stride = 32.f; }

            int hw = cell % HW;
            int na = cell / HW;
            int a = na % 3;
            int n = na / 3;
            int w = hw % W;
            int h = hw / W;
            int cell_lab = (n * HW + hw) * 3 + a;

            const float* fp = f + (size_t)n * 255 * HW + (size_t)a * 85 * HW + hw;
            float rx = fp[0];
            float ry = fp[HW];
            float rw = fp[2 * HW];
            float rh = fp[3 * HW];
            float rc = fp[4 * HW];

            float aw = d_anchors[level][a][0];
            float ah = d_anchors[level][a][1];
            float px = (1.f / (1.f + expf(-rx)) + (float)w) * stride;
            float py = (1.f / (1.f + expf(-ry)) + (float)h) * stride;
            float pw = expf(rw) * aw;
            float ph = expf(rh) * ah;

            int m = counts[level * NIMG + n];
            if (m > MAXB) m = MAXB;
            int base = (level * NIMG + n) * MAXB;
            float parea = pw * ph;
            float pl = px - pw * 0.5f, pr = px + pw * 0.5f;
            float pt = py - ph * 0.5f, pb = py + ph * 0.5f;
            float maxiou = 0.f;
            bool ispos = false;
            for (int i = 0; i < m; ++i) {
                float4 b = boxes[base + i];
                if (cellids[base + i] == cell_lab) ispos = true;
                float tl = b.x - b.z * 0.5f, tr = b.x + b.z * 0.5f;
                float tt = b.y - b.w * 0.5f, tb = b.y + b.w * 0.5f;
                float iw = fmaxf(fminf(pr, tr) - fmaxf(pl, tl), 0.f);
                float ih = fmaxf(fminf(pb, tb) - fmaxf(pt, tt), 0.f);
                float inter = iw * ih;
                float uni = parea + b.z * b.w - inter;
                float iou = inter / fmaxf(uni, 1e-9f);
                maxiou = fmaxf(maxiou, iou);
            }
            if (ispos)              conf = bce_logits(rc, 1.f);
            else if (maxiou < 0.5f) conf = bce_logits(rc, 0.f);
        }

        for (int off = 32; off > 0; off >>= 1) conf += __shfl_down(conf, off);
        __shared__ float sc[4];
        if (lane == 0) sc[wid] = conf;
        __syncthreads();
        if (threadIdx.x == 0)
            partial[1 * 1024 + cb] = sc[0] + sc[1] + sc[2] + sc[3];
    }

    // ---- epilogue: last-done block finalizes (no polling) ----
    __shared__ int amlast;
    __syncthreads();
    if (threadIdx.x == 0) {
        __threadfence();                     // publish this block's partials
        int d = atomicAdd(syncp, 1);
        amlast = (d == NALL - 1) ? 1 : 0;
    }
    __syncthreads();
    if (amlast) {
        __threadfence();                     // acquire others' partials
        float a0 = 0.f, a1 = 0.f, a2 = 0.f;
        for (int i = threadIdx.x; i < NBLK; i += 256) {
            a1 += partial[1 * 1024 + i];
            if (i < NPOS) {
                a0 += partial[0 * 1024 + i];
                a2 += partial[2 * 1024 + i];
            }
        }
        for (int off = 32; off > 0; off >>= 1) {
            a0 += __shfl_down(a0, off);
            a1 += __shfl_down(a1, off);
            a2 += __shfl_down(a2, off);
        }
        __shared__ float s[3][4];
        if (lane == 0) { s[0][wid] = a0; s[1][wid] = a1; s[2][wid] = a2; }
        __syncthreads();
        if (threadIdx.x == 0) {
            out[0] = (s[0][0] + s[0][1] + s[0][2] + s[0][3]) * (1.f / 16.f);
            out[1] = (s[1][0] + s[1][1] + s[1][2] + s[1][3]) * (1.f / 16.f);
            out[2] = (s[2][0] + s[2][1] + s[2][2] + s[2][3]) * (1.f / 16.f);
        }
    }
}

extern "C" void kernel_launch(void* const* d_in, const int* in_sizes, int n_in,
                              void* d_out, int out_size, void* d_ws, size_t ws_size,
                              hipStream_t stream) {
    const float* f0 = (const float*)d_in[0];
    const float* f1 = (const float*)d_in[1];
    const float* f2 = (const float*)d_in[2];
    const float* l0 = (const float*)d_in[3];
    const float* l1 = (const float*)d_in[4];
    const float* l2 = (const float*)d_in[5];
    float* out = (float*)d_out;

    int*    counts  = (int*)((char*)d_ws + WS_COUNTS);
    int*    syncp   = (int*)((char*)d_ws + WS_SYNC);
    float4* boxes   = (float4*)((char*)d_ws + WS_BOXES);
    int*    cellids = (int*)((char*)d_ws + WS_CELLIDS);
    float*  partial = (float*)((char*)d_ws + WS_PARTIAL);

    hipMemsetAsync(d_ws, 0, 256, stream);   // zero counts + done-counter

    scan_labels<<<NBLK, 256, 0, stream>>>(l0, l1, l2, counts, boxes, cellids);
    loss_fused<<<NALL, 256, 0, stream>>>(f0, f1, f2, l0, l1, l2,
                                         counts, syncp, boxes, cellids,
                                         partial, out);
}

// Round 9
// 133.971 us; speedup vs baseline: 1.6792x; 1.0890x over previous
//
#include <hip/hip_runtime.h>

// YOLO loss, 3 levels. Inputs (fp32):
//   d_in[0..2] = pred (N=16, C=255, H, W), d_in[3..5] = label (N, H, W, 3, 85)
// Output: d_out = [reg, conf, prob] fp32.
//
// R9 = revert to R6 champion (memset -> scan -> loss_fused -> finalize).
// R8's last-block epilogue fold REGRESSED (134->146): per-block device fence
// + 714 same-line atomics + final reduce all sit on the kernel critical path,
// costing more than the separate finalize dispatch it replaced. Kept from R8:
// positive blocks first (blockIdx 0..47) so their serial gather chains start
// at dispatch head.
//  scan:  conf-only gather (one 4B load per cell, stride 340 B) -> compact
//         positive boxes per (level,image). ~11 MB of cachelines.
//  loss:  blocks 0..47 = positives, ONE WAVE per box, prob channels spread
//         across lanes (2 wave-wide gathers, 64 misses in flight);
//         blocks 48..713 = conf loss per cell (coalesced channel planes,
//         zero label reads; membership via compacted cellids).
//  finalize: 1 block reduces partials -> out.

#define NIMG 16
#define MAXB 64

// per-level cell counts: N*3*H*W
#define C0 (16 * 3 * 52 * 52)   // 129792
#define C1 (16 * 3 * 26 * 26)   // 32448
#define C2 (16 * 3 * 13 * 13)   // 8112
#define CTOT (C0 + C1 + C2)     // 170352
#define NBLK ((CTOT + 255) / 256)  // 666 conf blocks
#define NPOS 48
#define NALL (NBLK + NPOS)         // 714 total blocks

// workspace layout (bytes); first 256 B zeroed by the memset
#define WS_COUNTS   0           // 48 ints
#define WS_BOXES    256         // 48*64 float4 = 49152
#define WS_CELLIDS  49408       // 48*64 int    = 12288
#define WS_PARTIAL  65536       // float[3][1024]: [0]=reg(48), [1]=conf(666), [2]=prob(48)

__device__ __constant__ float d_anchors[3][3][2] = {
    {{12.f, 16.f}, {19.f, 36.f}, {40.f, 28.f}},
    {{36.f, 75.f}, {76.f, 55.f}, {72.f, 146.f}},
    {{142.f, 110.f}, {192.f, 243.f}, {459.f, 401.f}}};

__device__ __forceinline__ float bce_logits(float x, float t) {
    return fmaxf(x, 0.f) - x * t + log1pf(expf(-fabsf(x)));
}

// ---------------- Kernel A: conf-only gather + positive compaction ----------
__global__ void scan_labels(const float* __restrict__ l0,
                            const float* __restrict__ l1,
                            const float* __restrict__ l2,
                            int* __restrict__ counts,
                            float4* __restrict__ boxes,
                            int* __restrict__ cellids) {
    int rec = blockIdx.x * blockDim.x + threadIdx.x;
    if (rec >= CTOT) return;

    const float* lab;
    int level, cell, hw3;
    if (rec < C0)           { level = 0; cell = rec;           lab = l0; hw3 = 3 * 52 * 52; }
    else if (rec < C0 + C1) { level = 1; cell = rec - C0;      lab = l1; hw3 = 3 * 26 * 26; }
    else                    { level = 2; cell = rec - C0 - C1; lab = l2; hw3 = 3 * 13 * 13; }

    const float* lp = lab + (size_t)cell * 85;
    float c = lp[4];                     // the only load for 99.92% of threads
    if (c > 0.f) {
        int n = cell / hw3;
        int p = atomicAdd(&counts[level * NIMG + n], 1);
        if (p < MAXB) {
            float4 b;
            b.x = lp[0]; b.y = lp[1]; b.z = lp[2]; b.w = lp[3];
            boxes[(level * NIMG + n) * MAXB + p] = b;
            cellids[(level * NIMG + n) * MAXB + p] = cell;
        }
    }
}

// ---------------- Kernel B: pos (blocks 0..47) + conf (blocks 48..713) ------
__global__ __launch_bounds__(256) void loss_fused(
        const float* __restrict__ f0,
        const float* __restrict__ f1,
        const float* __restrict__ f2,
        const float* __restrict__ l0,
        const float* __restrict__ l1,
        const float* __restrict__ l2,
        const int* __restrict__ counts,
        const float4* __restrict__ boxes,
        const int* __restrict__ cellids,
        float* __restrict__ partial) {
    int lane = threadIdx.x & 63;
    int wid = threadIdx.x >> 6;

    if (blockIdx.x < NPOS) {
        // ---- positives: one wave per box ----
        int pb = blockIdx.x;                 // 0..47 = (level, image)
        int lv = pb / NIMG;
        int n = pb % NIMG;
        const float *f, *lab;
        int Wp, HWp; float strp;
        if (lv == 0)      { f = f0; lab = l0; Wp = 52; HWp = 52 * 52; strp = 8.f; }
        else if (lv == 1) { f = f1; lab = l1; Wp = 26; HWp = 26 * 26; strp = 16.f; }
        else              { f = f2; lab = l2; Wp = 13; HWp = 13 * 13; strp = 32.f; }

        int m = counts[pb];
        if (m > MAXB) m = MAXB;
        int bbase = pb * MAXB;

        float reg_acc = 0.f, prob_acc = 0.f;
        for (int i = wid; i < m; i += 4) {   // one wave per positive box
            int pcell = cellids[bbase + i];  // (n*HW + hw)*3 + a
            float4 b = boxes[bbase + i];
            int a = pcell % 3;
            int hw = (pcell / 3) % HWp;
            int w = hw % Wp;
            int h = hw / Wp;
            const float* fp = f + ((size_t)n * 255 + (size_t)a * 85) * HWp + hw;
            const float* lp = lab + (size_t)pcell * 85;

            // lanes 0..39: prob ch (5+lane) & (45+lane); lanes 40..43: raw xy/wh
            int ch1 = (lane < 40) ? (5 + lane) : ((lane < 44) ? (lane - 40) : 0);
            float g1 = fp[(size_t)ch1 * HWp];
            float g2 = fp[(size_t)((lane < 40) ? (45 + lane) : 0) * HWp];
            float t1 = lp[(lane < 40) ? (5 + lane) : 0];
            float t2 = lp[(lane < 40) ? (45 + lane) : 0];

            float pp = (lane < 40) ? (bce_logits(g1, t1) + bce_logits(g2, t2)) : 0.f;
            for (int off = 32; off > 0; off >>= 1) pp += __shfl_down(pp, off);

            float prx = __shfl(g1, 40);
            float pry = __shfl(g1, 41);
            float prw = __shfl(g1, 42);
            float prh = __shfl(g1, 43);
            if (lane == 0) {
                prob_acc += pp;
                float aw = d_anchors[lv][a][0];
                float ah = d_anchors[lv][a][1];
                float ox = b.x / strp - (float)w;
                float oy = b.y / strp - (float)h;
                float ow = logf(b.z / aw + 1e-7f);
                float oh = logf(b.w / ah + 1e-7f);
                float scale = 2.f - b.z * b.w * (1.f / (416.f * 416.f));
                float dw = prw - ow, dh = prh - oh;
                reg_acc += scale * (bce_logits(prx, ox) + bce_logits(pry, oy))
                         + scale * 0.5f * (dw * dw + dh * dh);
            }
        }
        __shared__ float sp[2][4];
        if (lane == 0) { sp[0][wid] = reg_acc; sp[1][wid] = prob_acc; }
        __syncthreads();
        if (threadIdx.x == 0) {
            partial[0 * 1024 + pb] = sp[0][0] + sp[0][1] + sp[0][2] + sp[0][3];
            partial[2 * 1024 + pb] = sp[1][0] + sp[1][1] + sp[1][2] + sp[1][3];
        }
    } else {
        // ---- conf loss per cell; no label reads ----
        int cb = blockIdx.x - NPOS;          // 0..NBLK-1
        int gid = cb * blockDim.x + threadIdx.x;
        float conf = 0.f;

        if (gid < CTOT) {
            const float* f;
            int level, cell, W, HW;
            float stride;
            if (gid < C0)           { level = 0; cell = gid;           f = f0; W = 52; HW = 52 * 52; stride = 8.f; }
            else if (gid < C0 + C1) { level = 1; cell = gid - C0;      f = f1; W = 26; HW = 26 * 26; stride = 16.f; }
            else                    { level = 2; cell = gid - C0 - C1; f = f2; W = 13; HW = 13 * 13; stride = 32.f; }

            int hw = cell % HW;
            int na = cell / HW;
            int a = na % 3;
            int n = na / 3;
            int w = hw % W;
            int h = hw / W;
            int cell_lab = (n * HW + hw) * 3 + a;

            const float* fp = f + (size_t)n * 255 * HW + (size_t)a * 85 * HW + hw;
            float rx = fp[0];
            float ry = fp[HW];
            float rw = fp[2 * HW];
            float rh = fp[3 * HW];
            float rc = fp[4 * HW];

            float aw = d_anchors[level][a][0];
            float ah = d_anchors[level][a][1];
            float px = (1.f / (1.f + expf(-rx)) + (float)w) * stride;
            float py = (1.f / (1.f + expf(-ry)) + (float)h) * stride;
            float pw = expf(rw) * aw;
            float ph = expf(rh) * ah;

            int m = counts[level * NIMG + n];
            if (m > MAXB) m = MAXB;
            int base = (level * NIMG + n) * MAXB;
            float parea = pw * ph;
            float pl = px - pw * 0.5f, pr = px + pw * 0.5f;
            float pt = py - ph * 0.5f, pb = py + ph * 0.5f;
            float maxiou = 0.f;
            bool ispos = false;
            for (int i = 0; i < m; ++i) {
                float4 b = boxes[base + i];
                if (cellids[base + i] == cell_lab) ispos = true;
                float tl = b.x - b.z * 0.5f, tr = b.x + b.z * 0.5f;
                float tt = b.y - b.w * 0.5f, tb = b.y + b.w * 0.5f;
                float iw = fmaxf(fminf(pr, tr) - fmaxf(pl, tl), 0.f);
                float ih = fmaxf(fminf(pb, tb) - fmaxf(pt, tt), 0.f);
                float inter = iw * ih;
                float uni = parea + b.z * b.w - inter;
                float iou = inter / fmaxf(uni, 1e-9f);
                maxiou = fmaxf(maxiou, iou);
            }
            if (ispos)              conf = bce_logits(rc, 1.f);
            else if (maxiou < 0.5f) conf = bce_logits(rc, 0.f);
        }

        for (int off = 32; off > 0; off >>= 1) conf += __shfl_down(conf, off);
        __shared__ float sc[4];
        if (lane == 0) sc[wid] = conf;
        __syncthreads();
        if (threadIdx.x == 0)
            partial[1 * 1024 + cb] = sc[0] + sc[1] + sc[2] + sc[3];
    }
}

// ---------------- Kernel C: finalize (1 block) ----------------
__global__ void finalize(const float* __restrict__ partial,
                         float* __restrict__ out) {
    float a0 = 0.f, a1 = 0.f, a2 = 0.f;
    for (int i = threadIdx.x; i < NBLK; i += 256) {
        a1 += partial[1 * 1024 + i];
        if (i < NPOS) {
            a0 += partial[0 * 1024 + i];
            a2 += partial[2 * 1024 + i];
        }
    }
    for (int off = 32; off > 0; off >>= 1) {
        a0 += __shfl_down(a0, off);
        a1 += __shfl_down(a1, off);
        a2 += __shfl_down(a2, off);
    }
    __shared__ float s[3][4];
    int lane = threadIdx.x & 63;
    int wid = threadIdx.x >> 6;
    if (lane == 0) { s[0][wid] = a0; s[1][wid] = a1; s[2][wid] = a2; }
    __syncthreads();
    if (threadIdx.x == 0) {
        out[0] = (s[0][0] + s[0][1] + s[0][2] + s[0][3]) * (1.f / 16.f);
        out[1] = (s[1][0] + s[1][1] + s[1][2] + s[1][3]) * (1.f / 16.f);
        out[2] = (s[2][0] + s[2][1] + s[2][2] + s[2][3]) * (1.f / 16.f);
    }
}

extern "C" void kernel_launch(void* const* d_in, const int* in_sizes, int n_in,
                              void* d_out, int out_size, void* d_ws, size_t ws_size,
                              hipStream_t stream) {
    const float* f0 = (const float*)d_in[0];
    const float* f1 = (const float*)d_in[1];
    const float* f2 = (const float*)d_in[2];
    const float* l0 = (const float*)d_in[3];
    const float* l1 = (const float*)d_in[4];
    const float* l2 = (const float*)d_in[5];
    float* out = (float*)d_out;

    int*    counts  = (int*)((char*)d_ws + WS_COUNTS);
    float4* boxes   = (float4*)((char*)d_ws + WS_BOXES);
    int*    cellids = (int*)((char*)d_ws + WS_CELLIDS);
    float*  partial = (float*)((char*)d_ws + WS_PARTIAL);

    hipMemsetAsync(d_ws, 0, 256, stream);   // zero counts

    scan_labels<<<NBLK, 256, 0, stream>>>(l0, l1, l2, counts, boxes, cellids);
    loss_fused<<<NALL, 256, 0, stream>>>(f0, f1, f2, l0, l1, l2,
                                         counts, boxes, cellids, partial);
    finalize<<<1, 256, 0, stream>>>(partial, out);
}